// Round 1
// baseline (3006.367 us; speedup 1.0000x reference)
//
#include <hip/hip_runtime.h>
#include <float.h>

#define DIM 512
#define NQ  256
#define KK  5
#define BR  64          // memory rows per tile
#define KT  32          // k-tile depth
#define QS_STRIDE 260   // k-major Q tile row stride (multiple of 4 for float4 align)
#define MS_STRIDE 68    // k-major M tile row stride
#define D2_STRIDE 65    // d2 scratch row stride (+1 pad, b32 access)

// ---------------- kernel 0: q_sq ----------------
__global__ void qsq_kernel(const float* __restrict__ q, float* __restrict__ qsq) {
    int b = blockIdx.x;
    int t = threadIdx.x; // 64 threads = 1 wave
    const float* row = q + (size_t)b * DIM;
    float s = 0.f;
    #pragma unroll
    for (int i = 0; i < DIM / 64; ++i) {
        float v = row[t + i * 64];
        s += v * v;
    }
    #pragma unroll
    for (int off = 32; off > 0; off >>= 1) s += __shfl_down(s, off);
    if (t == 0) qsq[b] = s;
}

// ---------------- kernel 1: distances + per-block top-5 ----------------
__global__ __launch_bounds__(256, 2)
void knn_chunk_kernel(const float* __restrict__ q,
                      const float* __restrict__ m,
                      const float* __restrict__ qsq,
                      float* __restrict__ cand_d,
                      int*   __restrict__ cand_i,
                      int N, int tiles_per_block, int total_tiles)
{
    // union scratch: staging tiles (10496 floats) alias d2 scratch (16640 floats)
    __shared__ __attribute__((aligned(16))) float smem[NQ * D2_STRIDE]; // 66560 B
    __shared__ float msq[BR];

    float* Qs  = smem;                       // [KT][QS_STRIDE]
    float* Ms  = smem + KT * QS_STRIDE;      // [KT][MS_STRIDE]
    float* d2t = smem;                       // [NQ][D2_STRIDE] (after K-loop)

    const int tid = threadIdx.x;
    const int qi  = tid & 31;   // 0..31 : owns queries {4qi..4qi+3, 128+4qi..}
    const int ri  = tid >> 5;   // 0..7  : owns rows    {4ri..4ri+3, 32+4ri..}
    const int srow = tid >> 3;  // staging row 0..31
    const int sseg = tid & 7;   // staging float4 segment 0..7

    float topd[KK]; int topi[KK];
    #pragma unroll
    for (int j = 0; j < KK; ++j) { topd[j] = FLT_MAX; topi[j] = -1; }

    float qsq_reg[8];
    #pragma unroll
    for (int c = 0; c < 4; ++c) {
        qsq_reg[c]     = qsq[4 * qi + c];
        qsq_reg[4 + c] = qsq[128 + 4 * qi + c];
    }

    const int tile_begin = blockIdx.x * tiles_per_block;
    const int tile_end   = min(tile_begin + tiles_per_block, total_tiles);

    for (int tile = tile_begin; tile < tile_end; ++tile) {
        const int rowbase = tile * BR;

        float acc[8][8];
        #pragma unroll
        for (int i = 0; i < 8; ++i)
            #pragma unroll
            for (int j = 0; j < 8; ++j) acc[i][j] = 0.f;

        float msp0 = 0.f, msp1 = 0.f;
        __syncthreads(); // protect d2t/Qs alias from previous tile's selection

        for (int kt = 0; kt < DIM / KT; ++kt) {
            // ---- stage Q tile: 256 q x 32 k, k-major transpose ----
            #pragma unroll
            for (int i = 0; i < 8; ++i) {
                const int qrow = srow + 32 * i;
                const float4 v = *(const float4*)(q + (size_t)qrow * DIM + kt * KT + sseg * 4);
                Qs[(sseg * 4 + 0) * QS_STRIDE + qrow] = v.x;
                Qs[(sseg * 4 + 1) * QS_STRIDE + qrow] = v.y;
                Qs[(sseg * 4 + 2) * QS_STRIDE + qrow] = v.z;
                Qs[(sseg * 4 + 3) * QS_STRIDE + qrow] = v.w;
            }
            // ---- stage M tile: 64 rows x 32 k, k-major, accumulate row sumsq ----
            {
                int gr = rowbase + srow;
                float4 v = make_float4(0.f, 0.f, 0.f, 0.f);
                if (gr < N) v = *(const float4*)(m + (size_t)gr * DIM + kt * KT + sseg * 4);
                Ms[(sseg * 4 + 0) * MS_STRIDE + srow] = v.x;
                Ms[(sseg * 4 + 1) * MS_STRIDE + srow] = v.y;
                Ms[(sseg * 4 + 2) * MS_STRIDE + srow] = v.z;
                Ms[(sseg * 4 + 3) * MS_STRIDE + srow] = v.w;
                msp0 += v.x * v.x + v.y * v.y + v.z * v.z + v.w * v.w;

                gr = rowbase + srow + 32;
                v = make_float4(0.f, 0.f, 0.f, 0.f);
                if (gr < N) v = *(const float4*)(m + (size_t)gr * DIM + kt * KT + sseg * 4);
                Ms[(sseg * 4 + 0) * MS_STRIDE + srow + 32] = v.x;
                Ms[(sseg * 4 + 1) * MS_STRIDE + srow + 32] = v.y;
                Ms[(sseg * 4 + 2) * MS_STRIDE + srow + 32] = v.z;
                Ms[(sseg * 4 + 3) * MS_STRIDE + srow + 32] = v.w;
                msp1 += v.x * v.x + v.y * v.y + v.z * v.z + v.w * v.w;
            }
            __syncthreads();

            // ---- inner product: 8x8 outer product per thread ----
            #pragma unroll 8
            for (int k = 0; k < KT; ++k) {
                const float4 qa = *(const float4*)(Qs + k * QS_STRIDE + 4 * qi);
                const float4 qb = *(const float4*)(Qs + k * QS_STRIDE + 128 + 4 * qi);
                const float4 ma = *(const float4*)(Ms + k * MS_STRIDE + 4 * ri);
                const float4 mb = *(const float4*)(Ms + k * MS_STRIDE + 32 + 4 * ri);
                const float qf[8] = {qa.x, qa.y, qa.z, qa.w, qb.x, qb.y, qb.z, qb.w};
                const float mf[8] = {ma.x, ma.y, ma.z, ma.w, mb.x, mb.y, mb.z, mb.w};
                #pragma unroll
                for (int i = 0; i < 8; ++i)
                    #pragma unroll
                    for (int j = 0; j < 8; ++j)
                        acc[i][j] += qf[i] * mf[j];
            }
            __syncthreads();
        }

        // ---- reduce m_sq across the 8 staging lanes of each row ----
        {
            float s0 = msp0, s1 = msp1;
            #pragma unroll
            for (int off = 4; off > 0; off >>= 1) {
                s0 += __shfl_down(s0, off, 8);
                s1 += __shfl_down(s1, off, 8);
            }
            if ((tid & 7) == 0) { msq[srow] = s0; msq[srow + 32] = s1; }
        }
        __syncthreads();

        // ---- d2 = qsq + msq - 2*dot -> LDS scratch (aliases Qs/Ms, safe now) ----
        #pragma unroll
        for (int i = 0; i < 8; ++i) {
            const int qg = (i < 4) ? (4 * qi + i) : (128 + 4 * qi + (i - 4));
            #pragma unroll
            for (int j = 0; j < 8; ++j) {
                const int rr = (j < 4) ? (4 * ri + j) : (32 + 4 * ri + (j - 4));
                d2t[qg * D2_STRIDE + rr] = qsq_reg[i] + msq[rr] - 2.f * acc[i][j];
            }
        }
        __syncthreads();

        // ---- selection: thread tid owns query tid, scan 64 rows ----
        {
            const int nvalid = min(BR, N - rowbase);
            const float* row = d2t + tid * D2_STRIDE;
            for (int r = 0; r < nvalid; ++r) {
                float dd = row[r];
                if (dd < topd[KK - 1]) {
                    int ii = rowbase + r;
                    #pragma unroll
                    for (int s = 0; s < KK; ++s) {
                        if (dd < topd[s]) {
                            float td = topd[s]; int ti = topi[s];
                            topd[s] = dd; topi[s] = ii;
                            dd = td; ii = ti;
                        }
                    }
                }
            }
        }
        __syncthreads(); // before next tile overwrites d2t
    }

    #pragma unroll
    for (int j = 0; j < KK; ++j) {
        const size_t o = ((size_t)blockIdx.x * NQ + tid) * KK + j;
        cand_d[o] = topd[j];
        cand_i[o] = topi[j];
    }
}

// ---------------- kernel 2: merge per-block candidates ----------------
__global__ void merge_kernel(const float* __restrict__ cand_d,
                             const int*   __restrict__ cand_i,
                             float* __restrict__ out, int NB)
{
    __shared__ float sd[NQ * KK];
    __shared__ int   si[NQ * KK];
    const int qy = blockIdx.x;
    const int tid = threadIdx.x; // 256

    float topd[KK]; int topi[KK];
    #pragma unroll
    for (int j = 0; j < KK; ++j) { topd[j] = FLT_MAX; topi[j] = -1; }

    const int total = NB * KK;
    for (int c = tid; c < total; c += 256) {
        const int b = c / KK, j = c % KK;
        const size_t o = ((size_t)b * NQ + qy) * KK + j;
        float dd = cand_d[o];
        int   ii = cand_i[o];
        if (ii >= 0 && dd < topd[KK - 1]) {
            #pragma unroll
            for (int s = 0; s < KK; ++s) {
                if (dd < topd[s]) {
                    float td = topd[s]; int ti = topi[s];
                    topd[s] = dd; topi[s] = ii;
                    dd = td; ii = ti;
                }
            }
        }
    }
    #pragma unroll
    for (int j = 0; j < KK; ++j) { sd[tid * KK + j] = topd[j]; si[tid * KK + j] = topi[j]; }
    __syncthreads();

    if (tid == 0) {
        float fd[KK]; int fi[KK];
        #pragma unroll
        for (int j = 0; j < KK; ++j) { fd[j] = FLT_MAX; fi[j] = -1; }
        for (int c = 0; c < NQ * KK; ++c) {
            float dd = sd[c]; int ii = si[c];
            if (ii >= 0 && dd < fd[KK - 1]) {
                #pragma unroll
                for (int s = 0; s < KK; ++s) {
                    if (dd < fd[s]) {
                        float td = fd[s]; int ti = fi[s];
                        fd[s] = dd; fi[s] = ii;
                        dd = td; ii = ti;
                    }
                }
            }
        }
        // output: distances [256][5] then indices [256][5] (as float values)
        #pragma unroll
        for (int j = 0; j < KK; ++j) {
            out[qy * KK + j]            = fd[j];
            out[NQ * KK + qy * KK + j]  = (float)fi[j];
        }
    }
}

extern "C" void kernel_launch(void* const* d_in, const int* in_sizes, int n_in,
                              void* d_out, int out_size, void* d_ws, size_t ws_size,
                              hipStream_t stream) {
    const float* q = (const float*)d_in[0];
    const float* m = (const float*)d_in[1];
    // k is a device scalar; problem fixes k=5 (KK)
    const int N = in_sizes[1] / DIM;
    float* out = (float*)d_out;

    // workspace layout: [0,1024) qsq (256 f) | cand_d (NB*256*5 f) | cand_i (NB*256*5 i)
    float* qsq = (float*)d_ws;
    const int total_tiles = (N + BR - 1) / BR;

    const size_t per_block = (size_t)NQ * KK * (sizeof(float) + sizeof(int));
    const size_t avail = (ws_size > 1024) ? (ws_size - 1024) : 0;
    int NB = (int)(avail / per_block);
    if (NB < 1) NB = 1;
    if (NB > 977) NB = 977;                        // ~512 rows/block
    int tpb = (total_tiles + NB - 1) / NB;
    NB = (total_tiles + tpb - 1) / tpb;

    float* cand_d = (float*)((char*)d_ws + 1024);
    int*   cand_i = (int*)((char*)d_ws + 1024 + (size_t)NB * NQ * KK * sizeof(float));

    qsq_kernel<<<NQ, 64, 0, stream>>>(q, qsq);
    knn_chunk_kernel<<<NB, 256, 0, stream>>>(q, m, qsq, cand_d, cand_i,
                                             N, tpb, total_tiles);
    merge_kernel<<<NQ, 256, 0, stream>>>(cand_d, cand_i, out, NB);
}

// Round 2
// 1631.299 us; speedup vs baseline: 1.8429x; 1.8429x over previous
//
#include <hip/hip_runtime.h>
#include <float.h>

#define DIM 512
#define NQ  256
#define KK  5
#define TR  32            // memory rows per tile
#define SR  552           // LDS tile row stride in bf16 (1104 B = 276 words == 20 mod 32: 2-way free)
#define NBLK 256          // screening grid
#define CPB 8             // candidates kept per block per query
#define SHORTLIST 32      // rescored candidates per query

typedef __attribute__((ext_vector_type(8))) short short8;
typedef __attribute__((ext_vector_type(4))) float f32x4;

__device__ __forceinline__ unsigned short f2bf(float x) {
    unsigned u = __float_as_uint(x);
    u += 0x7FFFu + ((u >> 16) & 1u);   // round-to-nearest-even
    return (unsigned short)(u >> 16);
}

// ---------------- kernel 0: q_sq (identical to round 0) ----------------
__global__ void qsq_kernel(const float* __restrict__ q, float* __restrict__ qsq) {
    int b = blockIdx.x;
    int t = threadIdx.x; // 64 threads = 1 wave
    const float* row = q + (size_t)b * DIM;
    float s = 0.f;
    #pragma unroll
    for (int i = 0; i < DIM / 64; ++i) {
        float v = row[t + i * 64];
        s += v * v;
    }
    #pragma unroll
    for (int off = 32; off > 0; off >>= 1) s += __shfl_down(s, off);
    if (t == 0) qsq[b] = s;
}

// ---------------- kernel 1: bf16 MFMA screening ----------------
// 512 threads = 8 waves. Wave w holds queries [w*32, w*32+32) as resident
// A-fragments (full K). Memory rows streamed 32/tile, double-buffered LDS.
__global__ __launch_bounds__(512, 2)
void screen_kernel(const float* __restrict__ q, const float* __restrict__ m,
                   float* __restrict__ cand_d, int* __restrict__ cand_i, int N)
{
    __shared__ __align__(16) unsigned short mt[2][TR * SR];  // 2 x 35328 B
    __shared__ float msqh[2][TR * 2];
    __shared__ float msqv[2][TR];

    const int t    = threadIdx.x;
    const int w    = t >> 6;
    const int lane = t & 63;
    const int quad = lane >> 4;
    const int l15  = lane & 15;

    // tile range for this block
    const int T    = (N + TR - 1) / TR;
    const int base = T / NBLK, rem = T % NBLK;
    const int nt    = base + ((int)blockIdx.x < rem ? 1 : 0);
    const int tile0 = (int)blockIdx.x * base + min((int)blockIdx.x, rem);

    // ---- resident A fragments: A[m=lane&15][k=quad*8+j] ----
    short8 af[2][16];
    {
        #pragma unroll
        for (int qt = 0; qt < 2; ++qt) {
            const float* qp = q + (size_t)(w * 32 + qt * 16 + l15) * DIM + quad * 8;
            #pragma unroll
            for (int ks = 0; ks < 16; ++ks) {
                const float* p = qp + ks * 32;
                short8 f;
                #pragma unroll
                for (int e = 0; e < 8; ++e) f[e] = (short)f2bf(p[e]);
                af[qt][ks] = f;
            }
        }
    }

    float topd[CPB]; int topi[CPB];
    #pragma unroll
    for (int j = 0; j < CPB; ++j) { topd[j] = FLT_MAX; topi[j] = -1; }

    // ---- prologue: stage tile0 into buf 0 ----
    {
        const int rb = tile0 * TR;
        #pragma unroll
        for (int j = 0; j < 8; ++j) {
            const int flat4 = j * 512 + t;
            const int row = flat4 >> 7;           // all 64 lanes of a wave: same row
            const int k4  = flat4 & 127;
            const int gr  = min(rb + row, N - 1);
            const float4 v = *(const float4*)(m + (size_t)gr * DIM + k4 * 4);
            float s4 = v.x * v.x + v.y * v.y + v.z * v.z + v.w * v.w;
            #pragma unroll
            for (int off = 32; off > 0; off >>= 1) s4 += __shfl_down(s4, off);
            if (lane == 0) msqh[0][row * 2 + (w & 1)] = s4;
            ushort4 pk = make_ushort4(f2bf(v.x), f2bf(v.y), f2bf(v.z), f2bf(v.w));
            *(ushort4*)(&mt[0][row * SR + k4 * 4]) = pk;
        }
    }
    __syncthreads();
    if (t < TR) msqv[0][t] = ((tile0 * TR + t) < N) ? (msqh[0][2 * t] + msqh[0][2 * t + 1]) : 1e30f;

    for (int ti = 0; ti < nt; ++ti) {
        const int cur = ti & 1;
        const int nti = min(ti + 1, nt - 1);
        const int nrb = (tile0 + nti) * TR;

        // (1) issue global loads for next tile (hidden under MFMA)
        float4 ld[8];
        #pragma unroll
        for (int j = 0; j < 8; ++j) {
            const int flat4 = j * 512 + t;
            const int row = flat4 >> 7;
            const int k4  = flat4 & 127;
            const int gr  = min(nrb + row, N - 1);
            ld[j] = *(const float4*)(m + (size_t)gr * DIM + k4 * 4);
        }

        // (2) MFMA K-loop over current tile
        f32x4 acc00 = {0,0,0,0}, acc01 = {0,0,0,0}, acc10 = {0,0,0,0}, acc11 = {0,0,0,0};
        {
            const unsigned short* b0p = &mt[cur][l15 * SR + quad * 8];
            const unsigned short* b1p = b0p + 16 * SR;
            #pragma unroll
            for (int ks = 0; ks < 16; ++ks) {
                short8 b0 = *(const short8*)(b0p + ks * 32);
                short8 b1 = *(const short8*)(b1p + ks * 32);
                acc00 = __builtin_amdgcn_mfma_f32_16x16x32_bf16(af[0][ks], b0, acc00, 0, 0, 0);
                acc01 = __builtin_amdgcn_mfma_f32_16x16x32_bf16(af[0][ks], b1, acc01, 0, 0, 0);
                acc10 = __builtin_amdgcn_mfma_f32_16x16x32_bf16(af[1][ks], b0, acc10, 0, 0, 0);
                acc11 = __builtin_amdgcn_mfma_f32_16x16x32_bf16(af[1][ks], b1, acc11, 0, 0, 0);
            }
        }
        __syncthreads();   // all waves done reading mt[cur]

        // (4) screen scores (msq - 2*dot) -> scratch aliasing mt[cur]
        {
            float* scr = (float*)&mt[cur][0];   // [256][33] floats = 33792 B <= 35328
            const float ms0 = msqv[cur][l15];
            const float ms1 = msqv[cur][16 + l15];
            const int qb = w * 32 + quad * 4;
            #pragma unroll
            for (int r = 0; r < 4; ++r) {
                scr[(qb + r) * 33 + l15]           = ms0 - 2.f * acc00[r];
                scr[(qb + r) * 33 + 16 + l15]      = ms1 - 2.f * acc01[r];
                scr[(qb + 16 + r) * 33 + l15]      = ms0 - 2.f * acc10[r];
                scr[(qb + 16 + r) * 33 + 16 + l15] = ms1 - 2.f * acc11[r];
            }
        }

        // (5) convert + write next tile into the other buffer
        {
            unsigned short* nb = &mt[cur ^ 1][0];
            #pragma unroll
            for (int j = 0; j < 8; ++j) {
                const int flat4 = j * 512 + t;
                const int row = flat4 >> 7;
                const int k4  = flat4 & 127;
                const float4 v = ld[j];
                float s4 = v.x * v.x + v.y * v.y + v.z * v.z + v.w * v.w;
                #pragma unroll
                for (int off = 32; off > 0; off >>= 1) s4 += __shfl_down(s4, off);
                if (lane == 0) msqh[cur ^ 1][row * 2 + (w & 1)] = s4;
                ushort4 pk = make_ushort4(f2bf(v.x), f2bf(v.y), f2bf(v.z), f2bf(v.w));
                *(ushort4*)(&nb[row * SR + k4 * 4]) = pk;
            }
        }
        __syncthreads();   // staging complete; scr stable for scan
        if (t < TR) msqv[cur ^ 1][t] = (((tile0 + nti) * TR + t) < N)
                                       ? (msqh[cur ^ 1][2 * t] + msqh[cur ^ 1][2 * t + 1]) : 1e30f;

        // (7) selection scan: 2 threads per query, 16 rows each
        {
            const float* scr = (const float*)&mt[cur][0];
            const int qq = t >> 1, h = t & 1;
            const int ib = (tile0 + ti) * TR + h * 16;
            const float* srow = scr + qq * 33 + h * 16;
            #pragma unroll
            for (int r = 0; r < 16; ++r) {
                const float v = srow[r];
                if (v < topd[CPB - 1]) {
                    int ii = ib + r;
                    float dd = v;
                    #pragma unroll
                    for (int s = 0; s < CPB; ++s) {
                        if (dd < topd[s]) {
                            float td = topd[s]; int tv = topi[s];
                            topd[s] = dd; topi[s] = ii; dd = td; ii = tv;
                        }
                    }
                }
            }
        }
    }

    // ---- merge the two half-lists per query, emit block top-8 ----
    __syncthreads();
    float* hd = (float*)&mt[0][0];     // 512*8*4 = 16384 B
    int*   hi = (int*)&mt[1][0];
    #pragma unroll
    for (int j = 0; j < CPB; ++j) { hd[t * CPB + j] = topd[j]; hi[t * CPB + j] = topi[j]; }
    __syncthreads();
    if (t < NQ) {
        const float* da = hd + (2 * t) * CPB;     const int* ia = hi + (2 * t) * CPB;
        const float* db = hd + (2 * t + 1) * CPB; const int* ib = hi + (2 * t + 1) * CPB;
        int pa = 0, pb = 0;
        const size_t ob = ((size_t)blockIdx.x * NQ + t) * CPB;
        #pragma unroll
        for (int j = 0; j < CPB; ++j) {
            const float va = (pa < CPB) ? da[pa] : FLT_MAX;
            const float vb = (pb < CPB) ? db[pb] : FLT_MAX;
            if (va <= vb) { cand_d[ob + j] = va; cand_i[ob + j] = ia[pa]; ++pa; }
            else          { cand_d[ob + j] = vb; cand_i[ob + j] = ib[pb]; ++pb; }
        }
    }
}

// ---------------- kernel 2: merge + exact fp32 rescore ----------------
__global__ __launch_bounds__(256)
void merge_rescore_kernel(const float* __restrict__ cand_d, const int* __restrict__ cand_i,
                          const float* __restrict__ q, const float* __restrict__ m,
                          const float* __restrict__ qsq, float* __restrict__ out)
{
    __shared__ float sd[NBLK * CPB];
    __shared__ int   si[NBLK * CPB];
    __shared__ float wmv[4]; __shared__ int wmj[4];
    __shared__ int   sel[SHORTLIST];
    __shared__ __align__(16) float rows[8][DIM + 4];
    __shared__ float rd[SHORTLIST]; __shared__ int ri[SHORTLIST];

    const int qy = blockIdx.x;
    const int t = threadIdx.x;
    const int lane = t & 63, wid = t >> 6;

    #pragma unroll
    for (int j = 0; j < CPB; ++j) {
        sd[t * CPB + j] = cand_d[(size_t)t * NQ * CPB + (size_t)qy * CPB + j];
        si[t * CPB + j] = cand_i[(size_t)t * NQ * CPB + (size_t)qy * CPB + j];
    }
    __syncthreads();

    // extract bf16-score top-32
    for (int r = 0; r < SHORTLIST; ++r) {
        float mv = FLT_MAX; int mj = 0;
        #pragma unroll
        for (int j = 0; j < CPB; ++j) {
            const float v = sd[t * CPB + j];
            if (v < mv) { mv = v; mj = t * CPB + j; }
        }
        #pragma unroll
        for (int off = 32; off > 0; off >>= 1) {
            const float ov = __shfl_down(mv, off);
            const int   oj = __shfl_down(mj, off);
            if (ov < mv) { mv = ov; mj = oj; }
        }
        if (lane == 0) { wmv[wid] = mv; wmj[wid] = mj; }
        __syncthreads();
        if (t == 0) {
            float bv = FLT_MAX; int bj = 0;
            #pragma unroll
            for (int x = 0; x < 4; ++x) if (wmv[x] < bv) { bv = wmv[x]; bj = wmj[x]; }
            sel[r] = bj;
            sd[bj] = FLT_MAX;
        }
        __syncthreads();
    }

    const float qv = qsq[qy];

    for (int g = 0; g < SHORTLIST / 8; ++g) {
        {   // stage 8 candidate rows (coalesced)
            const int rr = t >> 5, c4 = t & 31;
            int mi = si[sel[g * 8 + rr]];
            if (mi < 0) mi = 0;
            #pragma unroll
            for (int x = 0; x < 4; ++x) {
                const int idx = x * 32 + c4;
                *(float4*)&rows[rr][idx * 4] = *(const float4*)(m + (size_t)mi * DIM + idx * 4);
            }
        }
        __syncthreads();
        if (t < 64) {
            const int c = t >> 3, j = t & 7;
            const int cnd = g * 8 + c;
            // msq: replicate round-0 summation order exactly
            float ms = 0.f;
            #pragma unroll
            for (int kt = 0; kt < 16; ++kt) {
                const float4 v = *(const float4*)&rows[c][kt * 32 + j * 4];
                ms += v.x * v.x + v.y * v.y + v.z * v.z + v.w * v.w;
            }
            #pragma unroll
            for (int off = 4; off > 0; off >>= 1) ms += __shfl_down(ms, off, 8);
            if (j == 0) {
                // dot: strict sequential k (round-0 order)
                float acc = 0.f;
                const float* qp = q + (size_t)qy * DIM;
                for (int k = 0; k < DIM; ++k) acc += qp[k] * rows[c][k];
                const int mi = si[sel[cnd]];
                rd[cnd] = (mi < 0) ? FLT_MAX : (qv + ms - 2.f * acc);
                ri[cnd] = mi;
            }
        }
        __syncthreads();
    }

    if (t == 0) {
        float fd[KK]; int fi[KK];
        #pragma unroll
        for (int j = 0; j < KK; ++j) { fd[j] = FLT_MAX; fi[j] = -1; }
        for (int c = 0; c < SHORTLIST; ++c) {
            float dd = rd[c]; int ii = ri[c];
            if (dd < fd[KK - 1]) {
                #pragma unroll
                for (int s = 0; s < KK; ++s) {
                    if (dd < fd[s]) {
                        float td = fd[s]; int tv = fi[s];
                        fd[s] = dd; fi[s] = ii; dd = td; ii = tv;
                    }
                }
            }
        }
        #pragma unroll
        for (int j = 0; j < KK; ++j) {
            out[qy * KK + j]           = fd[j];
            out[NQ * KK + qy * KK + j] = (float)fi[j];
        }
    }
}

extern "C" void kernel_launch(void* const* d_in, const int* in_sizes, int n_in,
                              void* d_out, int out_size, void* d_ws, size_t ws_size,
                              hipStream_t stream) {
    const float* q = (const float*)d_in[0];
    const float* m = (const float*)d_in[1];
    const int N = in_sizes[1] / DIM;
    float* out = (float*)d_out;

    float* qsq    = (float*)d_ws;
    float* cand_d = (float*)((char*)d_ws + 1024);
    int*   cand_i = (int*)((char*)d_ws + 1024 + (size_t)NBLK * NQ * CPB * sizeof(float));

    qsq_kernel<<<NQ, 64, 0, stream>>>(q, qsq);
    screen_kernel<<<NBLK, 512, 0, stream>>>(q, m, cand_d, cand_i, N);
    merge_rescore_kernel<<<NQ, 256, 0, stream>>>(cand_d, cand_i, q, m, qsq, out);
}